// Round 7
// baseline (349.617 us; speedup 1.0000x reference)
//
#include <hip/hip_runtime.h>
#include <hip/hip_bf16.h>
#include <math.h>

#define NGRAPH 128
#define NPG_   512
#define NN     (NGRAPH*NPG_)     // 65536 nodes
#define EPG    504
#define ETOT   (NGRAPH*EPG)      // 64512 real edges
#define HEADS  8
#define FDIM   512
#define NEG    0.2f

typedef __hip_bfloat16 bf16;
typedef __attribute__((ext_vector_type(8))) short short8;   // 8 bf16 = 4 VGPR
typedef __attribute__((ext_vector_type(4))) float f32x4;

static __device__ __forceinline__ float bf(short s){
  union { unsigned u; float f; } c; c.u = ((unsigned)(unsigned short)s) << 16; return c.f;
}
static __device__ __forceinline__ short fbf(float v){
  bf16 b = __float2bfloat16(v); return *(short*)&b;
}

static __device__ __forceinline__ void gload16(void* lds, const void* g){
  __builtin_amdgcn_global_load_lds((const __attribute__((address_space(1))) void*)g,
                                   (__attribute__((address_space(3))) void*)lds, 16, 0, 0);
}

// ---------------- workspace guard ----------------
__global__ void k_sentinel(float* out, int n){
  int i = blockIdx.x*blockDim.x + threadIdx.x;
  if (i < n) out[i] = 12345.0f;
}

// ---------------- one-kernel CSR build (block per graph) + coef (blocks 128..130) ----------------
__global__ __launch_bounds__(512) void k_csr(const int* __restrict__ ei, const float* __restrict__ ea,
                                             const float* __restrict__ We0, const float* __restrict__ ae0,
                                             const float* __restrict__ We1, const float* __restrict__ ae1,
                                             const float* __restrict__ We2, const float* __restrict__ ae2,
                                             int* __restrict__ deg_g, int* __restrict__ row_ptr,
                                             float* __restrict__ la,
                                             int* __restrict__ esrc, float* __restrict__ eattr,
                                             float* __restrict__ coef){
  int b = blockIdx.x;
  int t = threadIdx.x;
  if (b >= NGRAPH){                     // coef part: coef[l][h] = sum_c We[h*64+c]*ae[h*64+c]
    int l = b - NGRAPH;
    const float* We = l==0 ? We0 : (l==1 ? We1 : We2);
    const float* ae = l==0 ? ae0 : (l==1 ? ae1 : ae2);
    float v = We[t]*ae[t];
    #pragma unroll
    for (int o=32;o>0;o>>=1) v += __shfl_down(v, o);
    if ((t & 63) == 0) coef[l*HEADS + (t>>6)] = v;
    return;
  }
  __shared__ int   dg[512];
  __shared__ float ss[512];
  __shared__ int   scan[512];
  __shared__ int   cur[512];
  dg[t] = 0; ss[t] = 0.f;
  __syncthreads();
  int src=0, dst=0; float at=0.f;
  if (t < EPG){
    src = ei[(b*EPG+t)*2];
    dst = ei[(b*EPG+t)*2+1];
    at  = ea[b*EPG+t];
    atomicAdd(&dg[dst], 1);
    atomicAdd(&ss[dst], at);
  }
  __syncthreads();
  int d = dg[t];
  scan[t] = d;
  __syncthreads();
  for (int o=1;o<512;o<<=1){
    int v2 = (t>=o) ? scan[t-o] : 0;
    __syncthreads();
    scan[t] += v2;
    __syncthreads();
  }
  int excl = scan[t] - d;
  int n = b*NPG_ + t;
  row_ptr[n] = b*EPG + excl;
  deg_g[n]   = d;
  la[n]      = ss[t] / fmaxf((float)d, 1.f);
  cur[t] = excl;
  __syncthreads();
  if (t < EPG){
    int slot = atomicAdd(&cur[dst], 1);
    int p = b*EPG + slot;
    esrc[p]  = b*NPG_ + src;
    eattr[p] = at;
  }
}

// ---------------- W -> transposed bf16: Wt[n][k], layers 2,3 ----------------
__global__ void k_wt(const float* __restrict__ W1, const float* __restrict__ W2,
                     bf16* __restrict__ wt){
  int idx = blockIdx.x*blockDim.x + threadIdx.x;     // l*256K + n*512 + k
  if (idx >= 2*FDIM*FDIM) return;
  int l = idx >> 18;
  int r = idx & (FDIM*FDIM-1);
  int n = r >> 9, k = r & 511;
  const float* W = l ? W2 : W1;
  wt[idx] = __float2bfloat16(W[k*FDIM + n]);         // transposed read (L2-resident 1MB)
}

// ---------------- layer1 linear (K=3) + attention logits fused: wave per node ----------------
__global__ __launch_bounds__(256) void k_lin1_attn(const float* __restrict__ x,
                                                   const float* __restrict__ W,
                                                   const float* __restrict__ a_s,
                                                   const float* __restrict__ a_d,
                                                   bf16* __restrict__ xs,
                                                   float* __restrict__ als,
                                                   float* __restrict__ ald){
  int n = blockIdx.x*4 + (threadIdx.x >> 6);
  int lane = threadIdx.x & 63;
  int f0 = lane << 3;
  const float* xr = x + n*3;
  float x0 = xr[0], x1 = xr[1], x2 = xr[2];
  float v[8];
  short8 r;
  #pragma unroll
  for (int j=0;j<8;j++){
    v[j] = x0*W[f0+j] + x1*W[FDIM+f0+j] + x2*W[2*FDIM+f0+j];
    r[j] = fbf(v[j]);
  }
  ((short8*)(xs + (size_t)n*FDIM))[lane] = r;
  const float4* as4 = (const float4*)(a_s + f0);
  const float4* ad4 = (const float4*)(a_d + f0);
  float4 sa = as4[0], sb = as4[1];
  float4 da = ad4[0], db = ad4[1];
  float s = v[0]*sa.x + v[1]*sa.y + v[2]*sa.z + v[3]*sa.w
          + v[4]*sb.x + v[5]*sb.y + v[6]*sb.z + v[7]*sb.w;
  float d = v[0]*da.x + v[1]*da.y + v[2]*da.z + v[3]*da.w
          + v[4]*db.x + v[5]*db.y + v[6]*db.z + v[7]*db.w;
  #pragma unroll
  for (int o=1;o<8;o<<=1){ s += __shfl_xor(s, o); d += __shfl_xor(d, o); }
  if ((lane & 7) == 0){
    int hh = lane >> 3;
    als[n*HEADS+hh] = s;
    ald[n*HEADS+hh] = d;
  }
}

// ---------------- per-node attention logits: wave per node (layers 2,3) ----------------
__global__ __launch_bounds__(256) void k_attn_node(const bf16* __restrict__ xs,
                                                   const float* __restrict__ a_s,
                                                   const float* __restrict__ a_d,
                                                   float* __restrict__ als,
                                                   float* __restrict__ ald){
  int n = blockIdx.x*4 + (threadIdx.x >> 6);
  int lane = threadIdx.x & 63;
  short8 v = ((const short8*)(xs + (size_t)n*FDIM))[lane];
  const float4* as4 = (const float4*)a_s;
  const float4* ad4 = (const float4*)a_d;
  float4 sa = as4[lane*2], sb = as4[lane*2+1];
  float4 da = ad4[lane*2], db = ad4[lane*2+1];
  float s = bf(v[0])*sa.x + bf(v[1])*sa.y + bf(v[2])*sa.z + bf(v[3])*sa.w
          + bf(v[4])*sb.x + bf(v[5])*sb.y + bf(v[6])*sb.z + bf(v[7])*sb.w;
  float d = bf(v[0])*da.x + bf(v[1])*da.y + bf(v[2])*da.z + bf(v[3])*da.w
          + bf(v[4])*db.x + bf(v[5])*db.y + bf(v[6])*db.z + bf(v[7])*db.w;
  #pragma unroll
  for (int o=1;o<8;o<<=1){ s += __shfl_xor(s, o); d += __shfl_xor(d, o); }
  if ((lane & 7) == 0){
    int hh = lane >> 3;
    als[n*HEADS+hh] = s;
    ald[n*HEADS+hh] = d;
  }
}

// ---------------- fused GAT: single-pass online softmax; wave per node ----------------
__global__ __launch_bounds__(256) void k_gat(const bf16* __restrict__ xs,
                                             const float* __restrict__ als,
                                             const float* __restrict__ ald,
                                             const float* __restrict__ coef,
                                             const int* __restrict__ row_ptr,
                                             const int* __restrict__ deg,
                                             const int* __restrict__ esrc,
                                             const float* __restrict__ eattr,
                                             const float* __restrict__ la,
                                             const float* __restrict__ bias,
                                             int self,
                                             bf16* __restrict__ h){
  // XCD swizzle: contiguous chunk per XCD so each XCD's L2 sees few graphs at a time
  int nwg = gridDim.x;                   // 16384, %8 == 0
  int cpx = nwg >> 3;
  int bid = blockIdx.x;
  int swz = (bid & 7)*cpx + (bid >> 3);
  int n = swz*4 + (threadIdx.x >> 6);
  int lane = threadIdx.x & 63;
  int hh = lane >> 3;                    // head of my 8 features
  int row = row_ptr[n], d = deg[n];
  int tot = d + self;
  float aldn = ald[n*HEADS+hh];
  float ch = coef[hh];
  float lan = la[n];

  float m = -1e30f, ssum = 0.f;
  float acc[8] = {};
  for (int i=0;i<tot;i++){
    int s; float at;
    if (i<d){ s = esrc[row+i]; at = eattr[row+i]; }
    else    { s = n;           at = lan; }
    float raw = als[s*HEADS+hh] + aldn + at*ch;
    raw = raw > 0.f ? raw : NEG*raw;
    float mn = fmaxf(m, raw);
    float scale = __expf(m - mn);        // 1 if max unchanged; 0 on first iter
    float p = __expf(raw - mn);
    ssum = ssum*scale + p;
    short8 v = ((const short8*)(xs + (size_t)s*FDIM))[lane];
    #pragma unroll
    for (int j=0;j<8;j++) acc[j] = acc[j]*scale + p*bf(v[j]);
    m = mn;
  }
  float inv = 1.f / fmaxf(ssum, 1e-16f);
  const float4* b4 = (const float4*)bias;
  float4 ba = b4[lane*2], bb = b4[lane*2+1];
  float bias8[8] = {ba.x,ba.y,ba.z,ba.w,bb.x,bb.y,bb.z,bb.w};
  short8 r;
  #pragma unroll
  for (int j=0;j<8;j++){
    float o = acc[j]*inv + bias8[j];
    r[j] = fbf(o > 0.f ? o : 0.f);
  }
  ((short8*)(h + (size_t)n*FDIM))[lane] = r;
}

// ---------------- MFMA GEMM: C[M,N](bf16) = A[M,K](bf16) @ Wt^T ----------------
// A staged via global_load_lds (XOR-swizzled); B (1MB L2-resident Wt panel) loaded
// DIRECT global->reg, issued before the barrier so L2 latency hides under vmcnt drain.
// C epilogue goes through a chunk-XOR-swizzled LDS tile -> coalesced short8 stores.
__global__ __launch_bounds__(256) void gemm_mfma(const bf16* __restrict__ A,
                                                 const bf16* __restrict__ Wt,
                                                 bf16* __restrict__ C,
                                                 int M, int N, int K){
  __shared__ short As[128*64];     // 16 KB
  __shared__ short Cs[128*128];    // 32 KB
  int bid = blockIdx.x;
  int wk = ((bid & 7) << 8) | (bid >> 3);    // XCD chunk swizzle (2048 = 8*256)
  const int bm = (wk >> 2)*128, bn = (wk & 3)*128;
  const int tid = threadIdx.x;
  const int lane = tid & 63;
  const int w = tid >> 6;
  const int wm = (w >> 1)*64, wn = (w & 1)*64;
  const int lr = lane & 15;
  const int lk = lane >> 4;

  f32x4 acc[4][4] = {};
  const bf16* Bbase = Wt + (size_t)(bn + wn + lr)*K + lk*8;   // + ni*16*K + k0 + kk*32

  for (int k0 = 0; k0 < K; k0 += 64){
    // stage A tile (4 x global_load_lds, inverse-swizzled source)
    #pragma unroll
    for (int is = 0; is < 4; ++is){
      int i = is*256 + tid;            // granule id: row r, granule g
      int r = i >> 3, g = i & 7;
      int gs = g ^ (r & 7);
      gload16(&As[i*8], A + (size_t)(bm+r)*K + k0 + gs*8);
    }
    // B fragments direct to regs (L2-resident); in flight across the barrier drain
    short8 bfr[2][4];
    #pragma unroll
    for (int kk=0; kk<2; ++kk)
      #pragma unroll
      for (int ni=0; ni<4; ++ni)
        bfr[kk][ni] = *(const short8*)(Bbase + (size_t)ni*16*K + k0 + kk*32);
    __syncthreads();
    #pragma unroll
    for (int kk = 0; kk < 2; ++kk){
      short8 af[4];
      #pragma unroll
      for (int mi=0; mi<4; ++mi){
        int row = wm + mi*16 + lr;
        int g = (kk*4 + lk) ^ (row & 7);
        af[mi] = *(const short8*)&As[row*64 + g*8];
      }
      #pragma unroll
      for (int mi=0; mi<4; ++mi)
        #pragma unroll
        for (int ni=0; ni<4; ++ni)
          acc[mi][ni] = __builtin_amdgcn_mfma_f32_16x16x32_bf16(af[mi], bfr[kk][ni], acc[mi][ni], 0,0,0);
    }
    __syncthreads();
  }

  // epilogue: acc -> Cs (chunk-XOR swizzle) -> coalesced short8 stores
  // acc layout: col = lane&15 (+ni*16+wn), row = (lane>>4)*4 + reg (+mi*16+wm)
  #pragma unroll
  for (int mi=0; mi<4; ++mi)
    #pragma unroll
    for (int ni=0; ni<4; ++ni){
      int col = wn + ni*16 + lr;
      #pragma unroll
      for (int r=0; r<4; ++r){
        int row = wm + mi*16 + lk*4 + r;
        int chunk = (col >> 3) ^ (row & 7);
        Cs[row*128 + chunk*8 + (col & 7)] = fbf(acc[mi][ni][r]);
      }
    }
  __syncthreads();
  #pragma unroll
  for (int i2=0;i2<8;i2++){
    int id = i2*256 + tid;             // 2048 chunks of 8 shorts
    int row = id >> 4, c8 = id & 15;
    int chunk = c8 ^ (row & 7);
    short8 v = *(const short8*)&Cs[row*128 + chunk*8];
    ((short8*)(C + (size_t)(bm+row)*N + bn))[c8] = v;
  }
}

// ---------------- head part 1: per-16-node partial sums (vectorized) ----------------
__global__ __launch_bounds__(256) void k_gemb1(const bf16* __restrict__ h, float* __restrict__ pgemb){
  int gs_ = blockIdx.x;                 // g*8+s, 1024 blocks
  int g = gs_ >> 3, s = gs_ & 7;
  int t = threadIdx.x;
  int c = t & 63, rg = t >> 6;          // 4 row-groups of 16 rows
  const bf16* base = h + ((size_t)(g*NPG_ + s*64 + rg*16))*FDIM;
  float acc[8] = {};
  #pragma unroll 4
  for (int i=0;i<16;i++){
    short8 v = ((const short8*)(base + (size_t)i*FDIM))[c];
    #pragma unroll
    for (int j=0;j<8;j++) acc[j] += bf(v[j]);
  }
  float* dst = pgemb + ((size_t)(gs_*4 + rg))*FDIM + c*8;
  float4 lo = {acc[0],acc[1],acc[2],acc[3]};
  float4 hi = {acc[4],acc[5],acc[6],acc[7]};
  *(float4*)dst = lo;
  *(float4*)(dst+4) = hi;
}

// ---------------- head part 2: mean + FC1 + ReLU + FC2 fused, 4-way K-split ----------------
__global__ __launch_bounds__(1024) void k_head(const bf16* __restrict__ h,
                                               const float* __restrict__ pgemb,
                                               const float* __restrict__ fc1w,
                                               const float* __restrict__ fc1b,
                                               const float* __restrict__ fc2w,
                                               const float* __restrict__ fc2b,
                                               float* __restrict__ out){
  __shared__ float ge[FDIM];            // graph embedding (mean)
  __shared__ float ag[8][FDIM];         // 8 agent rows
  __shared__ float ps[2][8][257];       // agent-part partials (q=0,1)
  __shared__ float gs2[2][256];         // graph-part partials (q=2,3)
  __shared__ float f1[8][256];          // fc1 activations
  int g = blockIdx.x, t = threadIdx.x;

  if (t < FDIM){
    float s = 0.f;
    const float* p = pgemb + (size_t)g*32*FDIM + t;
    #pragma unroll
    for (int c=0;c<32;c++) s += p[(size_t)c*FDIM];
    ge[t] = s * (1.f/NPG_);
  } else {
    int i = t - FDIM;                   // 512 units: 8 rows x 64 short8
    int r = i >> 6, c = i & 63;
    short8 v = ((const short8*)(h + (size_t)(g*NPG_ + r)*FDIM))[c];
    #pragma unroll
    for (int j=0;j<8;j++) ag[r][c*8+j] = bf(v[j]);
  }
  __syncthreads();

  int col = t & 255, q = t >> 8;
  if (q < 2){
    float acc[8] = {};
    int kbeg = q*256;
    for (int k = kbeg; k < kbeg+256; k += 4){
      float w0 = fc1w[(k+0)*256+col];
      float w1 = fc1w[(k+1)*256+col];
      float w2 = fc1w[(k+2)*256+col];
      float w3 = fc1w[(k+3)*256+col];
      #pragma unroll
      for (int r=0;r<8;r++){
        float4 a = *(const float4*)&ag[r][k];
        acc[r] += a.x*w0 + a.y*w1 + a.z*w2 + a.w*w3;
      }
    }
    #pragma unroll
    for (int r=0;r<8;r++) ps[q][r][col] = acc[r];
  } else {
    float gacc = 0.f;
    int kbeg = (q-2)*256;
    for (int k = kbeg; k < kbeg+256; k += 4){
      float v0 = fc1w[(FDIM+k+0)*256+col];
      float v1 = fc1w[(FDIM+k+1)*256+col];
      float v2 = fc1w[(FDIM+k+2)*256+col];
      float v3 = fc1w[(FDIM+k+3)*256+col];
      float4 gv = *(const float4*)&ge[k];
      gacc += gv.x*v0 + gv.y*v1 + gv.z*v2 + gv.w*v3;
    }
    gs2[q-2][col] = gacc;
  }
  __syncthreads();

  if (t < 256){
    float b = fc1b[t] + gs2[0][t] + gs2[1][t];
    #pragma unroll
    for (int r=0;r<8;r++)
      f1[r][t] = fmaxf(ps[0][r][t] + ps[1][r][t] + b, 0.f);
  }
  __syncthreads();

  if (t < 128){
    int r = t >> 4, o = (t >> 3) & 1, l = t & 7;
    float s = 0.f;
    for (int k = l; k < 256; k += 8) s += f1[r][k] * fc2w[k*2+o];
    #pragma unroll
    for (int off=4; off; off>>=1) s += __shfl_down(s, off);
    if (l == 0) out[(g*8 + r)*2 + o] = s + fc2b[o];
  }
}

extern "C" void kernel_launch(void* const* d_in, const int* in_sizes, int n_in,
                              void* d_out, int out_size, void* d_ws, size_t ws_size,
                              hipStream_t stream)
{
  const float* x    = (const float*)d_in[0];
  const int*   ei   = (const int*)  d_in[1];
  const float* ea   = (const float*)d_in[2];
  const float* Wl[3]  = {(const float*)d_in[3],  (const float*)d_in[9],  (const float*)d_in[15]};
  const float* Bl[3]  = {(const float*)d_in[4],  (const float*)d_in[10], (const float*)d_in[16]};
  const float* ASl[3] = {(const float*)d_in[5],  (const float*)d_in[11], (const float*)d_in[17]};
  const float* ADl[3] = {(const float*)d_in[6],  (const float*)d_in[12], (const float*)d_in[18]};
  const float* WEl[3] = {(const float*)d_in[7],  (const float*)d_in[13], (const float*)d_in[19]};
  const float* AEl[3] = {(const float*)d_in[8],  (const float*)d_in[14], (const float*)d_in[20]};
  const float* FC1W = (const float*)d_in[21];
  const float* FC1B = (const float*)d_in[22];
  const float* FC2W = (const float*)d_in[23];
  const float* FC2B = (const float*)d_in[24];
  float* out = (float*)d_out;
  (void)in_sizes; (void)n_in;

  char* ws = (char*)d_ws;
  size_t off = 0;
  auto alloc = [&](size_t bytes)->char*{
    char* p = ws + off;
    off = (off + bytes + 255) & ~(size_t)255;
    return p;
  };
  bf16*  h       = (bf16*) alloc((size_t)NN*FDIM*2);    // 64 MB
  bf16*  xs      = (bf16*) alloc((size_t)NN*FDIM*2);    // 64 MB
  float* als     = (float*)alloc((size_t)NN*HEADS*4);   // 2 MB
  float* ald     = (float*)alloc((size_t)NN*HEADS*4);   // 2 MB
  float* la      = (float*)alloc((size_t)NN*4);
  int*   deg     = (int*)  alloc((size_t)NN*4);
  int*   row_ptr = (int*)  alloc((size_t)NN*4);
  int*   esrc    = (int*)  alloc((size_t)ETOT*4);
  float* eattr   = (float*)alloc((size_t)ETOT*4);
  float* coef    = (float*)alloc(3*HEADS*4);
  bf16*  wt      = (bf16*) alloc((size_t)2*FDIM*FDIM*2);  // layers 2,3 transposed bf16
  float* pgemb   = (float*)alloc((size_t)NGRAPH*32*FDIM*4); // 8 MB

  if (off > ws_size){
    k_sentinel<<<(out_size+255)/256, 256, 0, stream>>>(out, out_size);
    return;
  }

  // ---- CSR build + coef: one kernel (128 graph blocks + 3 coef blocks) ----
  k_csr<<<NGRAPH+3, 512, 0, stream>>>(ei, ea, WEl[0], AEl[0], WEl[1], AEl[1], WEl[2], AEl[2],
                                      deg, row_ptr, la, esrc, eattr, coef);
  k_wt<<<(2*FDIM*FDIM+255)/256, 256, 0, stream>>>(Wl[1], Wl[2], wt);

  // ---- layer 1 (no self loops), linear + logits fused ----
  k_lin1_attn<<<NN/4, 256, 0, stream>>>(x, Wl[0], ASl[0], ADl[0], xs, als, ald);
  k_gat<<<NN/4, 256, 0, stream>>>(xs, als, ald, coef, row_ptr, deg, esrc, eattr, la, Bl[0], 0, h);

  // ---- layers 2,3 (with self loops) ----
  for (int l=1;l<3;l++){
    gemm_mfma<<<2048, 256, 0, stream>>>(h, wt + (size_t)(l-1)*FDIM*FDIM, xs, NN, FDIM, FDIM);
    k_attn_node<<<NN/4, 256, 0, stream>>>(xs, ASl[l], ADl[l], als, ald);
    k_gat<<<NN/4, 256, 0, stream>>>(xs, als, ald, coef + l*HEADS, row_ptr, deg, esrc, eattr, la, Bl[l], 1, h);
  }

  // ---- head ----
  k_gemb1<<<NGRAPH*8, 256, 0, stream>>>(h, pgemb);
  k_head <<<NGRAPH, 1024, 0, stream>>>(h, pgemb, FC1W, FC1B, FC2W, FC2B, out);
}

// Round 8
// 265.533 us; speedup vs baseline: 1.3167x; 1.3167x over previous
//
#include <hip/hip_runtime.h>
#include <hip/hip_bf16.h>
#include <math.h>

#define NGRAPH 128
#define NPG_   512
#define NN     (NGRAPH*NPG_)     // 65536 nodes
#define EPG    504
#define ETOT   (NGRAPH*EPG)      // 64512 real edges
#define HEADS  8
#define FDIM   512
#define NEG    0.2f

typedef __hip_bfloat16 bf16;
typedef __attribute__((ext_vector_type(8))) short short8;   // 8 bf16 = 4 VGPR
typedef __attribute__((ext_vector_type(4))) float f32x4;

static __device__ __forceinline__ float bf(short s){
  union { unsigned u; float f; } c; c.u = ((unsigned)(unsigned short)s) << 16; return c.f;
}
static __device__ __forceinline__ short fbf(float v){
  bf16 b = __float2bfloat16(v); return *(short*)&b;
}

static __device__ __forceinline__ void gload16(void* lds, const void* g){
  __builtin_amdgcn_global_load_lds((const __attribute__((address_space(1))) void*)g,
                                   (__attribute__((address_space(3))) void*)lds, 16, 0, 0);
}

// ---------------- workspace guard ----------------
__global__ void k_sentinel(float* out, int n){
  int i = blockIdx.x*blockDim.x + threadIdx.x;
  if (i < n) out[i] = 12345.0f;
}

// ---------------- one-kernel CSR build (block per graph) + coef (blocks 128..130) ----------------
__global__ __launch_bounds__(512) void k_csr(const int* __restrict__ ei, const float* __restrict__ ea,
                                             const float* __restrict__ We0, const float* __restrict__ ae0,
                                             const float* __restrict__ We1, const float* __restrict__ ae1,
                                             const float* __restrict__ We2, const float* __restrict__ ae2,
                                             int* __restrict__ deg_g, int* __restrict__ row_ptr,
                                             float* __restrict__ la,
                                             int* __restrict__ esrc, float* __restrict__ eattr,
                                             float* __restrict__ coef){
  int b = blockIdx.x;
  int t = threadIdx.x;
  if (b >= NGRAPH){                     // coef part: coef[l][h] = sum_c We[h*64+c]*ae[h*64+c]
    int l = b - NGRAPH;
    const float* We = l==0 ? We0 : (l==1 ? We1 : We2);
    const float* ae = l==0 ? ae0 : (l==1 ? ae1 : ae2);
    float v = We[t]*ae[t];
    #pragma unroll
    for (int o=32;o>0;o>>=1) v += __shfl_down(v, o);
    if ((t & 63) == 0) coef[l*HEADS + (t>>6)] = v;
    return;
  }
  __shared__ int   dg[512];
  __shared__ float ss[512];
  __shared__ int   scan[512];
  __shared__ int   cur[512];
  dg[t] = 0; ss[t] = 0.f;
  __syncthreads();
  int src=0, dst=0; float at=0.f;
  if (t < EPG){
    src = ei[(b*EPG+t)*2];
    dst = ei[(b*EPG+t)*2+1];
    at  = ea[b*EPG+t];
    atomicAdd(&dg[dst], 1);
    atomicAdd(&ss[dst], at);
  }
  __syncthreads();
  int d = dg[t];
  scan[t] = d;
  __syncthreads();
  for (int o=1;o<512;o<<=1){
    int v2 = (t>=o) ? scan[t-o] : 0;
    __syncthreads();
    scan[t] += v2;
    __syncthreads();
  }
  int excl = scan[t] - d;
  int n = b*NPG_ + t;
  row_ptr[n] = b*EPG + excl;
  deg_g[n]   = d;
  la[n]      = ss[t] / fmaxf((float)d, 1.f);
  cur[t] = excl;
  __syncthreads();
  if (t < EPG){
    int slot = atomicAdd(&cur[dst], 1);
    int p = b*EPG + slot;
    esrc[p]  = b*NPG_ + src;
    eattr[p] = at;
  }
}

// ---------------- W -> transposed bf16: Wt[n][k], layers 2,3 ----------------
__global__ void k_wt(const float* __restrict__ W1, const float* __restrict__ W2,
                     bf16* __restrict__ wt){
  int idx = blockIdx.x*blockDim.x + threadIdx.x;     // l*256K + n*512 + k
  if (idx >= 2*FDIM*FDIM) return;
  int l = idx >> 18;
  int r = idx & (FDIM*FDIM-1);
  int n = r >> 9, k = r & 511;
  const float* W = l ? W2 : W1;
  wt[idx] = __float2bfloat16(W[k*FDIM + n]);         // transposed read (L2-resident 1MB)
}

// ---------------- fully-fused layer 1: lin1 recompute + logits + softmax + aggregate ----------------
// K=3 means a "gathered row" is recomputable from 12B of x: per edge, 3 broadcast scalar
// loads + 24 FMA/lane replaces a 1KB row gather. No xs materialization for layer 1.
__global__ __launch_bounds__(256) void k_gat1(const float* __restrict__ x,
                                              const float* __restrict__ W,
                                              const float* __restrict__ a_s,
                                              const float* __restrict__ a_d,
                                              const float* __restrict__ coef,
                                              const int* __restrict__ row_ptr,
                                              const int* __restrict__ deg,
                                              const int* __restrict__ esrc,
                                              const float* __restrict__ eattr,
                                              const float* __restrict__ bias,
                                              bf16* __restrict__ h){
  int nwg = gridDim.x;                   // 16384, %8 == 0
  int cpx = nwg >> 3;
  int bid = blockIdx.x;
  int swz = (bid & 7)*cpx + (bid >> 3);
  int n = swz*4 + (threadIdx.x >> 6);
  int lane = threadIdx.x & 63;
  int hh = lane >> 3;
  int f0 = lane << 3;

  float w0[8], w1[8], w2[8], as8[8], ad8[8];
  #pragma unroll
  for (int j=0;j<8;j+=4){
    *(float4*)&w0[j]  = *(const float4*)&W[f0+j];
    *(float4*)&w1[j]  = *(const float4*)&W[FDIM+f0+j];
    *(float4*)&w2[j]  = *(const float4*)&W[2*FDIM+f0+j];
    *(float4*)&as8[j] = *(const float4*)&a_s[f0+j];
    *(float4*)&ad8[j] = *(const float4*)&a_d[f0+j];
  }

  // own node: ald (dst logit)
  const float* xr = x + n*3;
  float x0 = xr[0], x1 = xr[1], x2 = xr[2];
  float dsum = 0.f;
  #pragma unroll
  for (int j=0;j<8;j++){
    float v = x0*w0[j] + x1*w1[j] + x2*w2[j];
    dsum += v*ad8[j];
  }
  #pragma unroll
  for (int o=1;o<8;o<<=1) dsum += __shfl_xor(dsum, o);
  float aldn = dsum;
  float ch = coef[hh];

  int row = row_ptr[n], d = deg[n];
  float m = -1e30f, ssum = 0.f;
  float acc[8] = {};
  for (int i=0;i<d;i++){
    int s = esrc[row+i]; float at = eattr[row+i];
    const float* xsr = x + s*3;
    float y0 = xsr[0], y1 = xsr[1], y2 = xsr[2];
    float v[8]; float ssrc = 0.f;
    #pragma unroll
    for (int j=0;j<8;j++){
      v[j] = y0*w0[j] + y1*w1[j] + y2*w2[j];
      ssrc += v[j]*as8[j];
    }
    #pragma unroll
    for (int o=1;o<8;o<<=1) ssrc += __shfl_xor(ssrc, o);
    float raw = ssrc + aldn + at*ch;
    raw = raw > 0.f ? raw : NEG*raw;
    float mn = fmaxf(m, raw);
    float sc = __expf(m - mn);
    float p  = __expf(raw - mn);
    ssum = ssum*sc + p;
    #pragma unroll
    for (int j=0;j<8;j++) acc[j] = acc[j]*sc + p*v[j];
    m = mn;
  }
  float inv = 1.f / fmaxf(ssum, 1e-16f);
  short8 r;
  #pragma unroll
  for (int j=0;j<8;j++){
    float o = acc[j]*inv + bias[f0+j];
    r[j] = fbf(o > 0.f ? o : 0.f);
  }
  ((short8*)(h + (size_t)n*FDIM))[lane] = r;
}

// ---------------- per-node attention logits: wave per node (layers 2,3) ----------------
__global__ __launch_bounds__(256) void k_attn_node(const bf16* __restrict__ xs,
                                                   const float* __restrict__ a_s,
                                                   const float* __restrict__ a_d,
                                                   float* __restrict__ als,
                                                   float* __restrict__ ald){
  int n = blockIdx.x*4 + (threadIdx.x >> 6);
  int lane = threadIdx.x & 63;
  short8 v = ((const short8*)(xs + (size_t)n*FDIM))[lane];
  const float4* as4 = (const float4*)a_s;
  const float4* ad4 = (const float4*)a_d;
  float4 sa = as4[lane*2], sb = as4[lane*2+1];
  float4 da = ad4[lane*2], db = ad4[lane*2+1];
  float s = bf(v[0])*sa.x + bf(v[1])*sa.y + bf(v[2])*sa.z + bf(v[3])*sa.w
          + bf(v[4])*sb.x + bf(v[5])*sb.y + bf(v[6])*sb.z + bf(v[7])*sb.w;
  float d = bf(v[0])*da.x + bf(v[1])*da.y + bf(v[2])*da.z + bf(v[3])*da.w
          + bf(v[4])*db.x + bf(v[5])*db.y + bf(v[6])*db.z + bf(v[7])*db.w;
  #pragma unroll
  for (int o=1;o<8;o<<=1){ s += __shfl_xor(s, o); d += __shfl_xor(d, o); }
  if ((lane & 7) == 0){
    int hh = lane >> 3;
    als[n*HEADS+hh] = s;
    ald[n*HEADS+hh] = d;
  }
}

// ---------------- fused GAT: single-pass online softmax; wave per node ----------------
__global__ __launch_bounds__(256) void k_gat(const bf16* __restrict__ xs,
                                             const float* __restrict__ als,
                                             const float* __restrict__ ald,
                                             const float* __restrict__ coef,
                                             const int* __restrict__ row_ptr,
                                             const int* __restrict__ deg,
                                             const int* __restrict__ esrc,
                                             const float* __restrict__ eattr,
                                             const float* __restrict__ la,
                                             const float* __restrict__ bias,
                                             bf16* __restrict__ h){
  int nwg = gridDim.x;                   // 16384, %8 == 0
  int cpx = nwg >> 3;
  int bid = blockIdx.x;
  int swz = (bid & 7)*cpx + (bid >> 3);
  int n = swz*4 + (threadIdx.x >> 6);
  int lane = threadIdx.x & 63;
  int hh = lane >> 3;                    // head of my 8 features
  int row = row_ptr[n], d = deg[n];
  int tot = d + 1;                       // self loop
  float aldn = ald[n*HEADS+hh];
  float ch = coef[hh];
  float lan = la[n];

  float m = -1e30f, ssum = 0.f;
  float acc[8] = {};
  for (int i=0;i<tot;i++){
    int s; float at;
    if (i<d){ s = esrc[row+i]; at = eattr[row+i]; }
    else    { s = n;           at = lan; }
    float raw = als[s*HEADS+hh] + aldn + at*ch;
    raw = raw > 0.f ? raw : NEG*raw;
    float mn = fmaxf(m, raw);
    float scale = __expf(m - mn);        // 1 if max unchanged; 0 on first iter
    float p = __expf(raw - mn);
    ssum = ssum*scale + p;
    short8 v = ((const short8*)(xs + (size_t)s*FDIM))[lane];
    #pragma unroll
    for (int j=0;j<8;j++) acc[j] = acc[j]*scale + p*bf(v[j]);
    m = mn;
  }
  float inv = 1.f / fmaxf(ssum, 1e-16f);
  const float4* b4 = (const float4*)bias;
  float4 ba = b4[lane*2], bb = b4[lane*2+1];
  float bias8[8] = {ba.x,ba.y,ba.z,ba.w,bb.x,bb.y,bb.z,bb.w};
  short8 r;
  #pragma unroll
  for (int j=0;j<8;j++){
    float o = acc[j]*inv + bias8[j];
    r[j] = fbf(o > 0.f ? o : 0.f);
  }
  ((short8*)(h + (size_t)n*FDIM))[lane] = r;
}

// ---------------- MFMA GEMM: C[M,N](bf16) = A[M,K](bf16) @ Wt^T (round-6 proven) ----------------
// 1-D grid 2048, XCD-chunk swizzle (N-minor): the 4 N-tiles sharing an A-panel run
// temporally adjacent on one XCD -> A re-reads are L2 hits. 32 KB LDS -> high occupancy.
__global__ __launch_bounds__(256) void gemm_mfma(const bf16* __restrict__ A,
                                                 const bf16* __restrict__ Wt,
                                                 bf16* __restrict__ C,
                                                 int M, int N, int K){
  __shared__ short As[128*64];
  __shared__ short Bs[128*64];
  int bid = blockIdx.x;
  int wk = ((bid & 7) << 8) | (bid >> 3);    // XCD chunk swizzle (2048 = 8*256)
  const int bm = (wk >> 2)*128, bn = (wk & 3)*128;
  const int tid = threadIdx.x;
  const int lane = tid & 63;
  const int w = tid >> 6;
  const int wm = (w >> 1)*64, wn = (w & 1)*64;
  const int lr = lane & 15;
  const int lk = lane >> 4;

  f32x4 acc[4][4] = {};

  for (int k0 = 0; k0 < K; k0 += 64){
    #pragma unroll
    for (int is = 0; is < 4; ++is){
      int i = is*256 + tid;            // granule id: row r, granule g
      int r = i >> 3, g = i & 7;
      int gs = g ^ (r & 7);            // inverse swizzle on source
      gload16(&As[i*8], A  + (size_t)(bm+r)*K + k0 + gs*8);
      gload16(&Bs[i*8], Wt + (size_t)(bn+r)*K + k0 + gs*8);
    }
    __syncthreads();
    #pragma unroll
    for (int kk = 0; kk < 2; ++kk){
      short8 af[4], bfr[4];
      #pragma unroll
      for (int mi=0; mi<4; ++mi){
        int row = wm + mi*16 + lr;
        int g = (kk*4 + lk) ^ (row & 7);
        af[mi] = *(const short8*)&As[row*64 + g*8];
      }
      #pragma unroll
      for (int ni=0; ni<4; ++ni){
        int row = wn + ni*16 + lr;
        int g = (kk*4 + lk) ^ (row & 7);
        bfr[ni] = *(const short8*)&Bs[row*64 + g*8];
      }
      #pragma unroll
      for (int mi=0; mi<4; ++mi)
        #pragma unroll
        for (int ni=0; ni<4; ++ni)
          acc[mi][ni] = __builtin_amdgcn_mfma_f32_16x16x32_bf16(af[mi], bfr[ni], acc[mi][ni], 0,0,0);
    }
    __syncthreads();
  }

  // epilogue: col = lane&15, row = (lane>>4)*4 + reg   (m89 layout)
  #pragma unroll
  for (int mi=0; mi<4; ++mi)
    #pragma unroll
    for (int ni=0; ni<4; ++ni){
      int col = bn + wn + ni*16 + lr;
      #pragma unroll
      for (int r=0; r<4; ++r){
        int rowg = bm + wm + mi*16 + lk*4 + r;
        C[(size_t)rowg*N + col] = __float2bfloat16(acc[mi][ni][r]);
      }
    }
}

// ---------------- head part 1: per-16-node partial sums (vectorized) ----------------
__global__ __launch_bounds__(256) void k_gemb1(const bf16* __restrict__ h, float* __restrict__ pgemb){
  int gs_ = blockIdx.x;                 // g*8+s, 1024 blocks
  int g = gs_ >> 3, s = gs_ & 7;
  int t = threadIdx.x;
  int c = t & 63, rg = t >> 6;          // 4 row-groups of 16 rows
  const bf16* base = h + ((size_t)(g*NPG_ + s*64 + rg*16))*FDIM;
  float acc[8] = {};
  #pragma unroll 4
  for (int i=0;i<16;i++){
    short8 v = ((const short8*)(base + (size_t)i*FDIM))[c];
    #pragma unroll
    for (int j=0;j<8;j++) acc[j] += bf(v[j]);
  }
  float* dst = pgemb + ((size_t)(gs_*4 + rg))*FDIM + c*8;
  float4 lo = {acc[0],acc[1],acc[2],acc[3]};
  float4 hi = {acc[4],acc[5],acc[6],acc[7]};
  *(float4*)dst = lo;
  *(float4*)(dst+4) = hi;
}

// ---------------- head part 2: mean + FC1 + ReLU + FC2 fused, 4-way K-split ----------------
__global__ __launch_bounds__(1024) void k_head(const bf16* __restrict__ h,
                                               const float* __restrict__ pgemb,
                                               const float* __restrict__ fc1w,
                                               const float* __restrict__ fc1b,
                                               const float* __restrict__ fc2w,
                                               const float* __restrict__ fc2b,
                                               float* __restrict__ out){
  __shared__ float ge[FDIM];            // graph embedding (mean)
  __shared__ float ag[8][FDIM];         // 8 agent rows
  __shared__ float ps[2][8][257];       // agent-part partials (q=0,1)
  __shared__ float gs2[2][256];         // graph-part partials (q=2,3)
  __shared__ float f1[8][256];          // fc1 activations
  int g = blockIdx.x, t = threadIdx.x;

  if (t < FDIM){
    float s = 0.f;
    const float* p = pgemb + (size_t)g*32*FDIM + t;
    #pragma unroll
    for (int c=0;c<32;c++) s += p[(size_t)c*FDIM];
    ge[t] = s * (1.f/NPG_);
  } else {
    int i = t - FDIM;                   // 512 units: 8 rows x 64 short8
    int r = i >> 6, c = i & 63;
    short8 v = ((const short8*)(h + (size_t)(g*NPG_ + r)*FDIM))[c];
    #pragma unroll
    for (int j=0;j<8;j++) ag[r][c*8+j] = bf(v[j]);
  }
  __syncthreads();

  int col = t & 255, q = t >> 8;
  if (q < 2){
    float acc[8] = {};
    int kbeg = q*256;
    for (int k = kbeg; k < kbeg+256; k += 4){
      float w0 = fc1w[(k+0)*256+col];
      float w1 = fc1w[(k+1)*256+col];
      float w2 = fc1w[(k+2)*256+col];
      float w3 = fc1w[(k+3)*256+col];
      #pragma unroll
      for (int r=0;r<8;r++){
        float4 a = *(const float4*)&ag[r][k];
        acc[r] += a.x*w0 + a.y*w1 + a.z*w2 + a.w*w3;
      }
    }
    #pragma unroll
    for (int r=0;r<8;r++) ps[q][r][col] = acc[r];
  } else {
    float gacc = 0.f;
    int kbeg = (q-2)*256;
    for (int k = kbeg; k < kbeg+256; k += 4){
      float v0 = fc1w[(FDIM+k+0)*256+col];
      float v1 = fc1w[(FDIM+k+1)*256+col];
      float v2 = fc1w[(FDIM+k+2)*256+col];
      float v3 = fc1w[(FDIM+k+3)*256+col];
      float4 gv = *(const float4*)&ge[k];
      gacc += gv.x*v0 + gv.y*v1 + gv.z*v2 + gv.w*v3;
    }
    gs2[q-2][col] = gacc;
  }
  __syncthreads();

  if (t < 256){
    float b = fc1b[t] + gs2[0][t] + gs2[1][t];
    #pragma unroll
    for (int r=0;r<8;r++)
      f1[r][t] = fmaxf(ps[0][r][t] + ps[1][r][t] + b, 0.f);
  }
  __syncthreads();

  if (t < 128){
    int r = t >> 4, o = (t >> 3) & 1, l = t & 7;
    float s = 0.f;
    for (int k = l; k < 256; k += 8) s += f1[r][k] * fc2w[k*2+o];
    #pragma unroll
    for (int off=4; off; off>>=1) s += __shfl_down(s, off);
    if (l == 0) out[(g*8 + r)*2 + o] = s + fc2b[o];
  }
}

extern "C" void kernel_launch(void* const* d_in, const int* in_sizes, int n_in,
                              void* d_out, int out_size, void* d_ws, size_t ws_size,
                              hipStream_t stream)
{
  const float* x    = (const float*)d_in[0];
  const int*   ei   = (const int*)  d_in[1];
  const float* ea   = (const float*)d_in[2];
  const float* Wl[3]  = {(const float*)d_in[3],  (const float*)d_in[9],  (const float*)d_in[15]};
  const float* Bl[3]  = {(const float*)d_in[4],  (const float*)d_in[10], (const float*)d_in[16]};
  const float* ASl[3] = {(const float*)d_in[5],  (const float*)d_in[11], (const float*)d_in[17]};
  const float* ADl[3] = {(const float*)d_in[6],  (const float*)d_in[12], (const float*)d_in[18]};
  const float* WEl[3] = {(const float*)d_in[7],  (const float*)d_in[13], (const float*)d_in[19]};
  const float* AEl[3] = {(const float*)d_in[8],  (const float*)d_in[14], (const float*)d_in[20]};
  const float* FC1W = (const float*)d_in[21];
  const float* FC1B = (const float*)d_in[22];
  const float* FC2W = (const float*)d_in[23];
  const float* FC2B = (const float*)d_in[24];
  float* out = (float*)d_out;
  (void)in_sizes; (void)n_in;

  char* ws = (char*)d_ws;
  size_t off = 0;
  auto alloc = [&](size_t bytes)->char*{
    char* p = ws + off;
    off = (off + bytes + 255) & ~(size_t)255;
    return p;
  };
  bf16*  h       = (bf16*) alloc((size_t)NN*FDIM*2);    // 64 MB
  bf16*  xs      = (bf16*) alloc((size_t)NN*FDIM*2);    // 64 MB
  float* als     = (float*)alloc((size_t)NN*HEADS*4);   // 2 MB
  float* ald     = (float*)alloc((size_t)NN*HEADS*4);   // 2 MB
  float* la      = (float*)alloc((size_t)NN*4);
  int*   deg     = (int*)  alloc((size_t)NN*4);
  int*   row_ptr = (int*)  alloc((size_t)NN*4);
  int*   esrc    = (int*)  alloc((size_t)ETOT*4);
  float* eattr   = (float*)alloc((size_t)ETOT*4);
  float* coef    = (float*)alloc(3*HEADS*4);
  bf16*  wt      = (bf16*) alloc((size_t)2*FDIM*FDIM*2);  // layers 2,3 transposed bf16
  float* pgemb   = (float*)alloc((size_t)NGRAPH*32*FDIM*4); // 8 MB

  if (off > ws_size){
    k_sentinel<<<(out_size+255)/256, 256, 0, stream>>>(out, out_size);
    return;
  }

  // ---- CSR build + coef: one kernel (128 graph blocks + 3 coef blocks) ----
  k_csr<<<NGRAPH+3, 512, 0, stream>>>(ei, ea, WEl[0], AEl[0], WEl[1], AEl[1], WEl[2], AEl[2],
                                      deg, row_ptr, la, esrc, eattr, coef);
  k_wt<<<(2*FDIM*FDIM+255)/256, 256, 0, stream>>>(Wl[1], Wl[2], wt);

  // ---- layer 1: fully fused (lin1 recompute + attention + aggregate) ----
  k_gat1<<<NN/4, 256, 0, stream>>>(x, Wl[0], ASl[0], ADl[0], coef, row_ptr, deg, esrc, eattr, Bl[0], h);

  // ---- layers 2,3 (with self loops) ----
  for (int l=1;l<3;l++){
    gemm_mfma<<<2048, 256, 0, stream>>>(h, wt + (size_t)(l-1)*FDIM*FDIM, xs, NN, FDIM, FDIM);
    k_attn_node<<<NN/4, 256, 0, stream>>>(xs, ASl[l], ADl[l], als, ald);
    k_gat<<<NN/4, 256, 0, stream>>>(xs, als, ald, coef + l*HEADS, row_ptr, deg, esrc, eattr, la, Bl[l], h);
  }

  // ---- head ----
  k_gemb1<<<NGRAPH*8, 256, 0, stream>>>(h, pgemb);
  k_head <<<NGRAPH, 1024, 0, stream>>>(h, pgemb, FC1W, FC1B, FC2W, FC2B, out);
}

// Round 9
// 255.087 us; speedup vs baseline: 1.3706x; 1.0410x over previous
//
#include <hip/hip_runtime.h>
#include <hip/hip_bf16.h>
#include <math.h>

#define NGRAPH 128
#define NPG_   512
#define NN     (NGRAPH*NPG_)     // 65536 nodes
#define EPG    504
#define ETOT   (NGRAPH*EPG)      // 64512 real edges
#define HEADS  8
#define FDIM   512
#define NEG    0.2f

typedef __hip_bfloat16 bf16;
typedef __attribute__((ext_vector_type(8))) short short8;   // 8 bf16 = 4 VGPR
typedef __attribute__((ext_vector_type(4))) float f32x4;

static __device__ __forceinline__ float bf(short s){
  union { unsigned u; float f; } c; c.u = ((unsigned)(unsigned short)s) << 16; return c.f;
}
static __device__ __forceinline__ short fbf(float v){
  bf16 b = __float2bfloat16(v); return *(short*)&b;
}

static __device__ __forceinline__ void gload16(void* lds, const void* g){
  __builtin_amdgcn_global_load_lds((const __attribute__((address_space(1))) void*)g,
                                   (__attribute__((address_space(3))) void*)lds, 16, 0, 0);
}

// ---------------- workspace guard ----------------
__global__ void k_sentinel(float* out, int n){
  int i = blockIdx.x*blockDim.x + threadIdx.x;
  if (i < n) out[i] = 12345.0f;
}

// ---- one-kernel CSR build (blocks 0..127) + coef (128..130) + layer1 ws/wd (131) ----
__global__ __launch_bounds__(512) void k_csr(const int* __restrict__ ei, const float* __restrict__ ea,
                                             const float* __restrict__ We0, const float* __restrict__ ae0,
                                             const float* __restrict__ We1, const float* __restrict__ ae1,
                                             const float* __restrict__ We2, const float* __restrict__ ae2,
                                             const float* __restrict__ W1,
                                             const float* __restrict__ as1, const float* __restrict__ ad1,
                                             int* __restrict__ deg_g, int* __restrict__ row_ptr,
                                             float* __restrict__ la,
                                             int* __restrict__ esrc, float* __restrict__ eattr,
                                             float* __restrict__ coef, float* __restrict__ wsd){
  int b = blockIdx.x;
  int t = threadIdx.x;
  if (b >= NGRAPH){
    if (b < NGRAPH+3){                  // coef[l][h] = sum_c We[h*64+c]*ae[h*64+c]
      int l = b - NGRAPH;
      const float* We = l==0 ? We0 : (l==1 ? We1 : We2);
      const float* ae = l==0 ? ae0 : (l==1 ? ae1 : ae2);
      float v = We[t]*ae[t];
      #pragma unroll
      for (int o=32;o>0;o>>=1) v += __shfl_down(v, o);
      if ((t & 63) == 0) coef[l*HEADS + (t>>6)] = v;
      return;
    }
    // layer-1 x-space attention vectors: ws[h][k] = sum_c W1[k*512+h*64+c]*as1[h*64+c]
    float as_v = as1[t], ad_v = ad1[t];
    float v[6] = { W1[t]*as_v, W1[512+t]*as_v, W1[1024+t]*as_v,
                   W1[t]*ad_v, W1[512+t]*ad_v, W1[1024+t]*ad_v };
    #pragma unroll
    for (int o=32;o>0;o>>=1){
      #pragma unroll
      for (int q=0;q<6;q++) v[q] += __shfl_down(v[q], o);
    }
    if ((t & 63) == 0){
      int w = t >> 6;
      wsd[w*3+0]    = v[0]; wsd[w*3+1]    = v[1]; wsd[w*3+2]    = v[2];
      wsd[24+w*3+0] = v[3]; wsd[24+w*3+1] = v[4]; wsd[24+w*3+2] = v[5];
    }
    return;
  }
  __shared__ int   dg[512];
  __shared__ float ss[512];
  __shared__ int   scan[512];
  __shared__ int   cur[512];
  dg[t] = 0; ss[t] = 0.f;
  __syncthreads();
  int src=0, dst=0; float at=0.f;
  if (t < EPG){
    src = ei[(b*EPG+t)*2];
    dst = ei[(b*EPG+t)*2+1];
    at  = ea[b*EPG+t];
    atomicAdd(&dg[dst], 1);
    atomicAdd(&ss[dst], at);
  }
  __syncthreads();
  int d = dg[t];
  scan[t] = d;
  __syncthreads();
  for (int o=1;o<512;o<<=1){
    int v2 = (t>=o) ? scan[t-o] : 0;
    __syncthreads();
    scan[t] += v2;
    __syncthreads();
  }
  int excl = scan[t] - d;
  int n = b*NPG_ + t;
  row_ptr[n] = b*EPG + excl;
  deg_g[n]   = d;
  la[n]      = ss[t] / fmaxf((float)d, 1.f);
  cur[t] = excl;
  __syncthreads();
  if (t < EPG){
    int slot = atomicAdd(&cur[dst], 1);
    int p = b*EPG + slot;
    esrc[p]  = b*NPG_ + src;
    eattr[p] = at;
  }
}

// ---------------- W -> transposed bf16: Wt[n][k], layers 2,3 ----------------
__global__ void k_wt(const float* __restrict__ W1, const float* __restrict__ W2,
                     bf16* __restrict__ wt){
  int idx = blockIdx.x*blockDim.x + threadIdx.x;     // l*256K + n*512 + k
  if (idx >= 2*FDIM*FDIM) return;
  int l = idx >> 18;
  int r = idx & (FDIM*FDIM-1);
  int n = r >> 9, k = r & 511;
  const float* W = l ? W2 : W1;
  wt[idx] = __float2bfloat16(W[k*FDIM + n]);         // transposed read (L2-resident 1MB)
}

// ---------------- fully-fused layer 1 in x-space (3-dim) ----------------
// Logit: als[s,h] = x_s . ws[h]  (3 FMA, no shuffles). Aggregation: accumulate
// acc3 = sum p*x_src (3-dim), project through W once in the epilogue (linearity).
__global__ __launch_bounds__(256) void k_gat1(const float* __restrict__ x,
                                              const float* __restrict__ W,
                                              const float* __restrict__ wsd,
                                              const float* __restrict__ coef,
                                              const int* __restrict__ row_ptr,
                                              const int* __restrict__ deg,
                                              const int* __restrict__ esrc,
                                              const float* __restrict__ eattr,
                                              const float* __restrict__ bias,
                                              bf16* __restrict__ h){
  int nwg = gridDim.x;                   // 16384, %8 == 0
  int cpx = nwg >> 3;
  int bid = blockIdx.x;
  int swz = (bid & 7)*cpx + (bid >> 3);
  int n = swz*4 + (threadIdx.x >> 6);
  int lane = threadIdx.x & 63;
  int hh = lane >> 3;
  int f0 = lane << 3;

  float ws0 = wsd[hh*3+0],    ws1 = wsd[hh*3+1],    ws2 = wsd[hh*3+2];
  float wd0 = wsd[24+hh*3+0], wd1 = wsd[24+hh*3+1], wd2 = wsd[24+hh*3+2];
  float ch = coef[hh];

  const float* xr = x + n*3;
  float aldn = xr[0]*wd0 + xr[1]*wd1 + xr[2]*wd2;

  int row = row_ptr[n], d = deg[n];
  float m = -1e30f, ssum = 0.f;
  float a0 = 0.f, a1 = 0.f, a2 = 0.f;
  for (int i=0;i<d;i++){
    int s = esrc[row+i]; float at = eattr[row+i];
    const float* xsr = x + s*3;
    float y0 = xsr[0], y1 = xsr[1], y2 = xsr[2];
    float raw = y0*ws0 + y1*ws1 + y2*ws2 + aldn + at*ch;
    raw = raw > 0.f ? raw : NEG*raw;
    float mn = fmaxf(m, raw);
    float sc = __expf(m - mn);
    float p  = __expf(raw - mn);
    ssum = ssum*sc + p;
    a0 = a0*sc + p*y0;
    a1 = a1*sc + p*y1;
    a2 = a2*sc + p*y2;
    m = mn;
  }
  float inv = 1.f / fmaxf(ssum, 1e-16f);
  a0 *= inv; a1 *= inv; a2 *= inv;

  float w0[8], w1[8], w2[8], b8[8];
  #pragma unroll
  for (int j=0;j<8;j+=4){
    *(float4*)&w0[j] = *(const float4*)&W[f0+j];
    *(float4*)&w1[j] = *(const float4*)&W[FDIM+f0+j];
    *(float4*)&w2[j] = *(const float4*)&W[2*FDIM+f0+j];
    *(float4*)&b8[j] = *(const float4*)&bias[f0+j];
  }
  short8 r;
  #pragma unroll
  for (int j=0;j<8;j++){
    float o = a0*w0[j] + a1*w1[j] + a2*w2[j] + b8[j];
    r[j] = fbf(o > 0.f ? o : 0.f);
  }
  ((short8*)(h + (size_t)n*FDIM))[lane] = r;
}

// ---------------- per-node attention logits: wave per node (layers 2,3) ----------------
__global__ __launch_bounds__(256) void k_attn_node(const bf16* __restrict__ xs,
                                                   const float* __restrict__ a_s,
                                                   const float* __restrict__ a_d,
                                                   float* __restrict__ als,
                                                   float* __restrict__ ald){
  int n = blockIdx.x*4 + (threadIdx.x >> 6);
  int lane = threadIdx.x & 63;
  short8 v = ((const short8*)(xs + (size_t)n*FDIM))[lane];
  const float4* as4 = (const float4*)a_s;
  const float4* ad4 = (const float4*)a_d;
  float4 sa = as4[lane*2], sb = as4[lane*2+1];
  float4 da = ad4[lane*2], db = ad4[lane*2+1];
  float s = bf(v[0])*sa.x + bf(v[1])*sa.y + bf(v[2])*sa.z + bf(v[3])*sa.w
          + bf(v[4])*sb.x + bf(v[5])*sb.y + bf(v[6])*sb.z + bf(v[7])*sb.w;
  float d = bf(v[0])*da.x + bf(v[1])*da.y + bf(v[2])*da.z + bf(v[3])*da.w
          + bf(v[4])*db.x + bf(v[5])*db.y + bf(v[6])*db.z + bf(v[7])*db.w;
  #pragma unroll
  for (int o=1;o<8;o<<=1){ s += __shfl_xor(s, o); d += __shfl_xor(d, o); }
  if ((lane & 7) == 0){
    int hh = lane >> 3;
    als[n*HEADS+hh] = s;
    ald[n*HEADS+hh] = d;
  }
}

// ---------------- fused GAT: single-pass online softmax; wave per node ----------------
__global__ __launch_bounds__(256) void k_gat(const bf16* __restrict__ xs,
                                             const float* __restrict__ als,
                                             const float* __restrict__ ald,
                                             const float* __restrict__ coef,
                                             const int* __restrict__ row_ptr,
                                             const int* __restrict__ deg,
                                             const int* __restrict__ esrc,
                                             const float* __restrict__ eattr,
                                             const float* __restrict__ la,
                                             const float* __restrict__ bias,
                                             bf16* __restrict__ h){
  int nwg = gridDim.x;                   // 16384, %8 == 0
  int cpx = nwg >> 3;
  int bid = blockIdx.x;
  int swz = (bid & 7)*cpx + (bid >> 3);
  int n = swz*4 + (threadIdx.x >> 6);
  int lane = threadIdx.x & 63;
  int hh = lane >> 3;                    // head of my 8 features
  int row = row_ptr[n], d = deg[n];
  int tot = d + 1;                       // self loop
  float aldn = ald[n*HEADS+hh];
  float ch = coef[hh];
  float lan = la[n];

  float m = -1e30f, ssum = 0.f;
  float acc[8] = {};
  for (int i=0;i<tot;i++){
    int s; float at;
    if (i<d){ s = esrc[row+i]; at = eattr[row+i]; }
    else    { s = n;           at = lan; }
    float raw = als[s*HEADS+hh] + aldn + at*ch;
    raw = raw > 0.f ? raw : NEG*raw;
    float mn = fmaxf(m, raw);
    float scale = __expf(m - mn);        // 1 if max unchanged; 0 on first iter
    float p = __expf(raw - mn);
    ssum = ssum*scale + p;
    short8 v = ((const short8*)(xs + (size_t)s*FDIM))[lane];
    #pragma unroll
    for (int j=0;j<8;j++) acc[j] = acc[j]*scale + p*bf(v[j]);
    m = mn;
  }
  float inv = 1.f / fmaxf(ssum, 1e-16f);
  const float4* b4 = (const float4*)bias;
  float4 ba = b4[lane*2], bb = b4[lane*2+1];
  float bias8[8] = {ba.x,ba.y,ba.z,ba.w,bb.x,bb.y,bb.z,bb.w};
  short8 r;
  #pragma unroll
  for (int j=0;j<8;j++){
    float o = acc[j]*inv + bias8[j];
    r[j] = fbf(o > 0.f ? o : 0.f);
  }
  ((short8*)(h + (size_t)n*FDIM))[lane] = r;
}

// ---------------- MFMA GEMM: C[M,N](bf16) = A[M,K](bf16) @ Wt^T (round-6 proven) ----------------
__global__ __launch_bounds__(256) void gemm_mfma(const bf16* __restrict__ A,
                                                 const bf16* __restrict__ Wt,
                                                 bf16* __restrict__ C,
                                                 int M, int N, int K){
  __shared__ short As[128*64];
  __shared__ short Bs[128*64];
  int bid = blockIdx.x;
  int wk = ((bid & 7) << 8) | (bid >> 3);    // XCD chunk swizzle (2048 = 8*256)
  const int bm = (wk >> 2)*128, bn = (wk & 3)*128;
  const int tid = threadIdx.x;
  const int lane = tid & 63;
  const int w = tid >> 6;
  const int wm = (w >> 1)*64, wn = (w & 1)*64;
  const int lr = lane & 15;
  const int lk = lane >> 4;

  f32x4 acc[4][4] = {};

  for (int k0 = 0; k0 < K; k0 += 64){
    #pragma unroll
    for (int is = 0; is < 4; ++is){
      int i = is*256 + tid;            // granule id: row r, granule g
      int r = i >> 3, g = i & 7;
      int gs = g ^ (r & 7);            // inverse swizzle on source
      gload16(&As[i*8], A  + (size_t)(bm+r)*K + k0 + gs*8);
      gload16(&Bs[i*8], Wt + (size_t)(bn+r)*K + k0 + gs*8);
    }
    __syncthreads();
    #pragma unroll
    for (int kk = 0; kk < 2; ++kk){
      short8 af[4], bfr[4];
      #pragma unroll
      for (int mi=0; mi<4; ++mi){
        int row = wm + mi*16 + lr;
        int g = (kk*4 + lk) ^ (row & 7);
        af[mi] = *(const short8*)&As[row*64 + g*8];
      }
      #pragma unroll
      for (int ni=0; ni<4; ++ni){
        int row = wn + ni*16 + lr;
        int g = (kk*4 + lk) ^ (row & 7);
        bfr[ni] = *(const short8*)&Bs[row*64 + g*8];
      }
      #pragma unroll
      for (int mi=0; mi<4; ++mi)
        #pragma unroll
        for (int ni=0; ni<4; ++ni)
          acc[mi][ni] = __builtin_amdgcn_mfma_f32_16x16x32_bf16(af[mi], bfr[ni], acc[mi][ni], 0,0,0);
    }
    __syncthreads();
  }

  // epilogue: col = lane&15, row = (lane>>4)*4 + reg   (m89 layout)
  #pragma unroll
  for (int mi=0; mi<4; ++mi)
    #pragma unroll
    for (int ni=0; ni<4; ++ni){
      int col = bn + wn + ni*16 + lr;
      #pragma unroll
      for (int r=0; r<4; ++r){
        int rowg = bm + wm + mi*16 + lk*4 + r;
        C[(size_t)rowg*N + col] = __float2bfloat16(acc[mi][ni][r]);
      }
    }
}

// ---------------- head part 1: per-16-node partial sums (vectorized) ----------------
__global__ __launch_bounds__(256) void k_gemb1(const bf16* __restrict__ h, float* __restrict__ pgemb){
  int gs_ = blockIdx.x;                 // g*8+s, 1024 blocks
  int g = gs_ >> 3, s = gs_ & 7;
  int t = threadIdx.x;
  int c = t & 63, rg = t >> 6;          // 4 row-groups of 16 rows
  const bf16* base = h + ((size_t)(g*NPG_ + s*64 + rg*16))*FDIM;
  float acc[8] = {};
  #pragma unroll 4
  for (int i=0;i<16;i++){
    short8 v = ((const short8*)(base + (size_t)i*FDIM))[c];
    #pragma unroll
    for (int j=0;j<8;j++) acc[j] += bf(v[j]);
  }
  float* dst = pgemb + ((size_t)(gs_*4 + rg))*FDIM + c*8;
  float4 lo = {acc[0],acc[1],acc[2],acc[3]};
  float4 hi = {acc[4],acc[5],acc[6],acc[7]};
  *(float4*)dst = lo;
  *(float4*)(dst+4) = hi;
}

// ---------------- head part 2: mean + FC1 + ReLU + FC2 fused, 4-way K-split ----------------
__global__ __launch_bounds__(1024) void k_head(const bf16* __restrict__ h,
                                               const float* __restrict__ pgemb,
                                               const float* __restrict__ fc1w,
                                               const float* __restrict__ fc1b,
                                               const float* __restrict__ fc2w,
                                               const float* __restrict__ fc2b,
                                               float* __restrict__ out){
  __shared__ float ge[FDIM];            // graph embedding (mean)
  __shared__ float ag[8][FDIM];         // 8 agent rows
  __shared__ float ps[2][8][257];       // agent-part partials (q=0,1)
  __shared__ float gs2[2][256];         // graph-part partials (q=2,3)
  __shared__ float f1[8][256];          // fc1 activations
  int g = blockIdx.x, t = threadIdx.x;

  if (t < FDIM){
    float s = 0.f;
    const float* p = pgemb + (size_t)g*32*FDIM + t;
    #pragma unroll
    for (int c=0;c<32;c++) s += p[(size_t)c*FDIM];
    ge[t] = s * (1.f/NPG_);
  } else {
    int i = t - FDIM;                   // 512 units: 8 rows x 64 short8
    int r = i >> 6, c = i & 63;
    short8 v = ((const short8*)(h + (size_t)(g*NPG_ + r)*FDIM))[c];
    #pragma unroll
    for (int j=0;j<8;j++) ag[r][c*8+j] = bf(v[j]);
  }
  __syncthreads();

  int col = t & 255, q = t >> 8;
  if (q < 2){
    float acc[8] = {};
    int kbeg = q*256;
    for (int k = kbeg; k < kbeg+256; k += 4){
      float w0 = fc1w[(k+0)*256+col];
      float w1 = fc1w[(k+1)*256+col];
      float w2 = fc1w[(k+2)*256+col];
      float w3 = fc1w[(k+3)*256+col];
      #pragma unroll
      for (int r=0;r<8;r++){
        float4 a = *(const float4*)&ag[r][k];
        acc[r] += a.x*w0 + a.y*w1 + a.z*w2 + a.w*w3;
      }
    }
    #pragma unroll
    for (int r=0;r<8;r++) ps[q][r][col] = acc[r];
  } else {
    float gacc = 0.f;
    int kbeg = (q-2)*256;
    for (int k = kbeg; k < kbeg+256; k += 4){
      float v0 = fc1w[(FDIM+k+0)*256+col];
      float v1 = fc1w[(FDIM+k+1)*256+col];
      float v2 = fc1w[(FDIM+k+2)*256+col];
      float v3 = fc1w[(FDIM+k+3)*256+col];
      float4 gv = *(const float4*)&ge[k];
      gacc += gv.x*v0 + gv.y*v1 + gv.z*v2 + gv.w*v3;
    }
    gs2[q-2][col] = gacc;
  }
  __syncthreads();

  if (t < 256){
    float b = fc1b[t] + gs2[0][t] + gs2[1][t];
    #pragma unroll
    for (int r=0;r<8;r++)
      f1[r][t] = fmaxf(ps[0][r][t] + ps[1][r][t] + b, 0.f);
  }
  __syncthreads();

  if (t < 128){
    int r = t >> 4, o = (t >> 3) & 1, l = t & 7;
    float s = 0.f;
    for (int k = l; k < 256; k += 8) s += f1[r][k] * fc2w[k*2+o];
    #pragma unroll
    for (int off=4; off; off>>=1) s += __shfl_down(s, off);
    if (l == 0) out[(g*8 + r)*2 + o] = s + fc2b[o];
  }
}

extern "C" void kernel_launch(void* const* d_in, const int* in_sizes, int n_in,
                              void* d_out, int out_size, void* d_ws, size_t ws_size,
                              hipStream_t stream)
{
  const float* x    = (const float*)d_in[0];
  const int*   ei   = (const int*)  d_in[1];
  const float* ea   = (const float*)d_in[2];
  const float* Wl[3]  = {(const float*)d_in[3],  (const float*)d_in[9],  (const float*)d_in[15]};
  const float* Bl[3]  = {(const float*)d_in[4],  (const float*)d_in[10], (const float*)d_in[16]};
  const float* ASl[3] = {(const float*)d_in[5],  (const float*)d_in[11], (const float*)d_in[17]};
  const float* ADl[3] = {(const float*)d_in[6],  (const float*)d_in[12], (const float*)d_in[18]};
  const float* WEl[3] = {(const float*)d_in[7],  (const float*)d_in[13], (const float*)d_in[19]};
  const float* AEl[3] = {(const float*)d_in[8],  (const float*)d_in[14], (const float*)d_in[20]};
  const float* FC1W = (const float*)d_in[21];
  const float* FC1B = (const float*)d_in[22];
  const float* FC2W = (const float*)d_in[23];
  const float* FC2B = (const float*)d_in[24];
  float* out = (float*)d_out;
  (void)in_sizes; (void)n_in;

  char* ws = (char*)d_ws;
  size_t off = 0;
  auto alloc = [&](size_t bytes)->char*{
    char* p = ws + off;
    off = (off + bytes + 255) & ~(size_t)255;
    return p;
  };
  bf16*  h       = (bf16*) alloc((size_t)NN*FDIM*2);    // 64 MB
  bf16*  xs      = (bf16*) alloc((size_t)NN*FDIM*2);    // 64 MB
  float* als     = (float*)alloc((size_t)NN*HEADS*4);   // 2 MB
  float* ald     = (float*)alloc((size_t)NN*HEADS*4);   // 2 MB
  float* la      = (float*)alloc((size_t)NN*4);
  int*   deg     = (int*)  alloc((size_t)NN*4);
  int*   row_ptr = (int*)  alloc((size_t)NN*4);
  int*   esrc    = (int*)  alloc((size_t)ETOT*4);
  float* eattr   = (float*)alloc((size_t)ETOT*4);
  float* coef    = (float*)alloc(3*HEADS*4);
  float* wsd     = (float*)alloc(48*4);
  bf16*  wt      = (bf16*) alloc((size_t)2*FDIM*FDIM*2);  // layers 2,3 transposed bf16
  float* pgemb   = (float*)alloc((size_t)NGRAPH*32*FDIM*4); // 8 MB

  if (off > ws_size){
    k_sentinel<<<(out_size+255)/256, 256, 0, stream>>>(out, out_size);
    return;
  }

  // ---- CSR build + coef + layer1 ws/wd: one kernel ----
  k_csr<<<NGRAPH+4, 512, 0, stream>>>(ei, ea, WEl[0], AEl[0], WEl[1], AEl[1], WEl[2], AEl[2],
                                      Wl[0], ASl[0], ADl[0],
                                      deg, row_ptr, la, esrc, eattr, coef, wsd);
  k_wt<<<(2*FDIM*FDIM+255)/256, 256, 0, stream>>>(Wl[1], Wl[2], wt);

  // ---- layer 1: fully fused in x-space ----
  k_gat1<<<NN/4, 256, 0, stream>>>(x, Wl[0], wsd, coef, row_ptr, deg, esrc, eattr, Bl[0], h);

  // ---- layers 2,3 (with self loops) ----
  for (int l=1;l<3;l++){
    gemm_mfma<<<2048, 256, 0, stream>>>(h, wt + (size_t)(l-1)*FDIM*FDIM, xs, NN, FDIM, FDIM);
    k_attn_node<<<NN/4, 256, 0, stream>>>(xs, ASl[l], ADl[l], als, ald);
    k_gat<<<NN/4, 256, 0, stream>>>(xs, als, ald, coef + l*HEADS, row_ptr, deg, esrc, eattr, la, Bl[l], h);
  }

  // ---- head ----
  k_gemb1<<<NGRAPH*8, 256, 0, stream>>>(h, pgemb);
  k_head <<<NGRAPH, 1024, 0, stream>>>(h, pgemb, FC1W, FC1B, FC2W, FC2B, out);
}

// Round 11
// 240.654 us; speedup vs baseline: 1.4528x; 1.0600x over previous
//
#include <hip/hip_runtime.h>
#include <hip/hip_bf16.h>
#include <math.h>

#define NGRAPH 128
#define NPG_   512
#define NN     (NGRAPH*NPG_)     // 65536 nodes
#define EPG    504
#define ETOT   (NGRAPH*EPG)      // 64512 real edges
#define HEADS  8
#define FDIM   512
#define NEG    0.2f

typedef __hip_bfloat16 bf16;
typedef __attribute__((ext_vector_type(8))) short short8;   // 8 bf16 = 4 VGPR
typedef __attribute__((ext_vector_type(4))) float f32x4;

static __device__ __forceinline__ float bf(short s){
  union { unsigned u; float f; } c; c.u = ((unsigned)(unsigned short)s) << 16; return c.f;
}
static __device__ __forceinline__ short fbf(float v){
  bf16 b = __float2bfloat16(v); return *(short*)&b;
}

static __device__ __forceinline__ void gload16(void* lds, const void* g){
  __builtin_amdgcn_global_load_lds((const __attribute__((address_space(1))) void*)g,
                                   (__attribute__((address_space(3))) void*)lds, 16, 0, 0);
}

// ---------------- workspace guard ----------------
__global__ void k_sentinel(float* out, int n){
  int i = blockIdx.x*blockDim.x + threadIdx.x;
  if (i < n) out[i] = 12345.0f;
}

// ---- one-kernel CSR build (blocks 0..127) + coef (128..130) + layer1 ws/wd (131) ----
__global__ __launch_bounds__(512) void k_csr(const int* __restrict__ ei, const float* __restrict__ ea,
                                             const float* __restrict__ We0, const float* __restrict__ ae0,
                                             const float* __restrict__ We1, const float* __restrict__ ae1,
                                             const float* __restrict__ We2, const float* __restrict__ ae2,
                                             const float* __restrict__ W1,
                                             const float* __restrict__ as1, const float* __restrict__ ad1,
                                             int* __restrict__ deg_g, int* __restrict__ row_ptr,
                                             float* __restrict__ la,
                                             int* __restrict__ esrc, float* __restrict__ eattr,
                                             float* __restrict__ coef, float* __restrict__ wsd){
  int b = blockIdx.x;
  int t = threadIdx.x;
  if (b >= NGRAPH){
    if (b < NGRAPH+3){                  // coef[l][h] = sum_c We[h*64+c]*ae[h*64+c]
      int l = b - NGRAPH;
      const float* We = l==0 ? We0 : (l==1 ? We1 : We2);
      const float* ae = l==0 ? ae0 : (l==1 ? ae1 : ae2);
      float v = We[t]*ae[t];
      #pragma unroll
      for (int o=32;o>0;o>>=1) v += __shfl_down(v, o);
      if ((t & 63) == 0) coef[l*HEADS + (t>>6)] = v;
      return;
    }
    // layer-1 x-space attention vectors: ws[h][k] = sum_c W1[k*512+h*64+c]*as1[h*64+c]
    float as_v = as1[t], ad_v = ad1[t];
    float v[6] = { W1[t]*as_v, W1[512+t]*as_v, W1[1024+t]*as_v,
                   W1[t]*ad_v, W1[512+t]*ad_v, W1[1024+t]*ad_v };
    #pragma unroll
    for (int o=32;o>0;o>>=1){
      #pragma unroll
      for (int q=0;q<6;q++) v[q] += __shfl_down(v[q], o);
    }
    if ((t & 63) == 0){
      int w = t >> 6;
      wsd[w*3+0]    = v[0]; wsd[w*3+1]    = v[1]; wsd[w*3+2]    = v[2];
      wsd[24+w*3+0] = v[3]; wsd[24+w*3+1] = v[4]; wsd[24+w*3+2] = v[5];
    }
    return;
  }
  __shared__ int   dg[512];
  __shared__ float ss[512];
  __shared__ int   scan[512];
  __shared__ int   cur[512];
  dg[t] = 0; ss[t] = 0.f;
  __syncthreads();
  int src=0, dst=0; float at=0.f;
  if (t < EPG){
    src = ei[(b*EPG+t)*2];
    dst = ei[(b*EPG+t)*2+1];
    at  = ea[b*EPG+t];
    atomicAdd(&dg[dst], 1);
    atomicAdd(&ss[dst], at);
  }
  __syncthreads();
  int d = dg[t];
  scan[t] = d;
  __syncthreads();
  for (int o=1;o<512;o<<=1){
    int v2 = (t>=o) ? scan[t-o] : 0;
    __syncthreads();
    scan[t] += v2;
    __syncthreads();
  }
  int excl = scan[t] - d;
  int n = b*NPG_ + t;
  row_ptr[n] = b*EPG + excl;
  deg_g[n]   = d;
  la[n]      = ss[t] / fmaxf((float)d, 1.f);
  cur[t] = excl;
  __syncthreads();
  if (t < EPG){
    int slot = atomicAdd(&cur[dst], 1);
    int p = b*EPG + slot;
    esrc[p]  = b*NPG_ + src;
    eattr[p] = at;
  }
}

// ---------------- W -> transposed bf16: Wt[n][k], layers 2,3 ----------------
__global__ void k_wt(const float* __restrict__ W1, const float* __restrict__ W2,
                     bf16* __restrict__ wt){
  int idx = blockIdx.x*blockDim.x + threadIdx.x;     // l*256K + n*512 + k
  if (idx >= 2*FDIM*FDIM) return;
  int l = idx >> 18;
  int r = idx & (FDIM*FDIM-1);
  int n = r >> 9, k = r & 511;
  const float* W = l ? W2 : W1;
  wt[idx] = __float2bfloat16(W[k*FDIM + n]);         // transposed read (L2-resident 1MB)
}

// ---------------- fully-fused layer 1 in x-space (3-dim) ----------------
__global__ __launch_bounds__(256) void k_gat1(const float* __restrict__ x,
                                              const float* __restrict__ W,
                                              const float* __restrict__ wsd,
                                              const float* __restrict__ coef,
                                              const int* __restrict__ row_ptr,
                                              const int* __restrict__ deg,
                                              const int* __restrict__ esrc,
                                              const float* __restrict__ eattr,
                                              const float* __restrict__ bias,
                                              bf16* __restrict__ h){
  int nwg = gridDim.x;                   // 16384, %8 == 0
  int cpx = nwg >> 3;
  int bid = blockIdx.x;
  int swz = (bid & 7)*cpx + (bid >> 3);
  int n = swz*4 + (threadIdx.x >> 6);
  int lane = threadIdx.x & 63;
  int hh = lane >> 3;
  int f0 = lane << 3;

  float ws0 = wsd[hh*3+0],    ws1 = wsd[hh*3+1],    ws2 = wsd[hh*3+2];
  float wd0 = wsd[24+hh*3+0], wd1 = wsd[24+hh*3+1], wd2 = wsd[24+hh*3+2];
  float ch = coef[hh];

  const float* xr = x + n*3;
  float aldn = xr[0]*wd0 + xr[1]*wd1 + xr[2]*wd2;

  int row = row_ptr[n], d = deg[n];
  float m = -1e30f, ssum = 0.f;
  float a0 = 0.f, a1 = 0.f, a2 = 0.f;
  for (int i=0;i<d;i++){
    int s = esrc[row+i]; float at = eattr[row+i];
    const float* xsr = x + s*3;
    float y0 = xsr[0], y1 = xsr[1], y2 = xsr[2];
    float raw = y0*ws0 + y1*ws1 + y2*ws2 + aldn + at*ch;
    raw = raw > 0.f ? raw : NEG*raw;
    float mn = fmaxf(m, raw);
    float sc = __expf(m - mn);
    float p  = __expf(raw - mn);
    ssum = ssum*sc + p;
    a0 = a0*sc + p*y0;
    a1 = a1*sc + p*y1;
    a2 = a2*sc + p*y2;
    m = mn;
  }
  float inv = 1.f / fmaxf(ssum, 1e-16f);
  a0 *= inv; a1 *= inv; a2 *= inv;

  float w0[8], w1[8], w2[8], b8[8];
  #pragma unroll
  for (int j=0;j<8;j+=4){
    *(float4*)&w0[j] = *(const float4*)&W[f0+j];
    *(float4*)&w1[j] = *(const float4*)&W[FDIM+f0+j];
    *(float4*)&w2[j] = *(const float4*)&W[2*FDIM+f0+j];
    *(float4*)&b8[j] = *(const float4*)&bias[f0+j];
  }
  short8 r;
  #pragma unroll
  for (int j=0;j<8;j++){
    float o = a0*w0[j] + a1*w1[j] + a2*w2[j] + b8[j];
    r[j] = fbf(o > 0.f ? o : 0.f);
  }
  ((short8*)(h + (size_t)n*FDIM))[lane] = r;
}

// ---------------- fused GAT: single-pass online softmax; wave per node ----------------
__global__ __launch_bounds__(256) void k_gat(const bf16* __restrict__ xs,
                                             const float* __restrict__ als,
                                             const float* __restrict__ ald,
                                             const float* __restrict__ coef,
                                             const int* __restrict__ row_ptr,
                                             const int* __restrict__ deg,
                                             const int* __restrict__ esrc,
                                             const float* __restrict__ eattr,
                                             const float* __restrict__ la,
                                             const float* __restrict__ bias,
                                             bf16* __restrict__ h){
  int nwg = gridDim.x;                   // 16384, %8 == 0
  int cpx = nwg >> 3;
  int bid = blockIdx.x;
  int swz = (bid & 7)*cpx + (bid >> 3);
  int n = swz*4 + (threadIdx.x >> 6);
  int lane = threadIdx.x & 63;
  int hh = lane >> 3;                    // head of my 8 features
  int row = row_ptr[n], d = deg[n];
  int tot = d + 1;                       // self loop
  float aldn = ald[n*HEADS+hh];
  float ch = coef[hh];
  float lan = la[n];

  float m = -1e30f, ssum = 0.f;
  float acc[8] = {};
  for (int i=0;i<tot;i++){
    int s; float at;
    if (i<d){ s = esrc[row+i]; at = eattr[row+i]; }
    else    { s = n;           at = lan; }
    float raw = als[s*HEADS+hh] + aldn + at*ch;
    raw = raw > 0.f ? raw : NEG*raw;
    float mn = fmaxf(m, raw);
    float scale = __expf(m - mn);        // 1 if max unchanged; 0 on first iter
    float p = __expf(raw - mn);
    ssum = ssum*scale + p;
    short8 v = ((const short8*)(xs + (size_t)s*FDIM))[lane];
    #pragma unroll
    for (int j=0;j<8;j++) acc[j] = acc[j]*scale + p*bf(v[j]);
    m = mn;
  }
  float inv = 1.f / fmaxf(ssum, 1e-16f);
  const float4* b4 = (const float4*)bias;
  float4 ba = b4[lane*2], bb = b4[lane*2+1];
  float bias8[8] = {ba.x,ba.y,ba.z,ba.w,bb.x,bb.y,bb.z,bb.w};
  short8 r;
  #pragma unroll
  for (int j=0;j<8;j++){
    float o = acc[j]*inv + bias8[j];
    r[j] = fbf(o > 0.f ? o : 0.f);
  }
  ((short8*)(h + (size_t)n*FDIM))[lane] = r;
}

// ---------------- MFMA GEMM + attention logits in epilogue (plain stores) ----------------
// Each wave's 64 cols = exactly one head block; its 64 rows are exclusive to it ->
// every (row, head) logit has a unique writer: no atomics, no pre-zeroing.
__global__ __launch_bounds__(256) void gemm_mfma(const bf16* __restrict__ A,
                                                 const bf16* __restrict__ Wt,
                                                 const float* __restrict__ a_s,
                                                 const float* __restrict__ a_d,
                                                 bf16* __restrict__ C,
                                                 float* __restrict__ als,
                                                 float* __restrict__ ald,
                                                 int M, int N, int K){
  __shared__ short As[128*64];
  __shared__ short Bs[128*64];
  int bid = blockIdx.x;
  int wk = ((bid & 7) << 8) | (bid >> 3);    // XCD chunk swizzle (2048 = 8*256)
  const int bm = (wk >> 2)*128, bn = (wk & 3)*128;
  const int tid = threadIdx.x;
  const int lane = tid & 63;
  const int w = tid >> 6;
  const int wm = (w >> 1)*64, wn = (w & 1)*64;
  const int lr = lane & 15;
  const int lk = lane >> 4;

  f32x4 acc[4][4] = {};

  for (int k0 = 0; k0 < K; k0 += 64){
    #pragma unroll
    for (int is = 0; is < 4; ++is){
      int i = is*256 + tid;            // granule id: row r, granule g
      int r = i >> 3, g = i & 7;
      int gs = g ^ (r & 7);            // inverse swizzle on source
      gload16(&As[i*8], A  + (size_t)(bm+r)*K + k0 + gs*8);
      gload16(&Bs[i*8], Wt + (size_t)(bn+r)*K + k0 + gs*8);
    }
    __syncthreads();
    #pragma unroll
    for (int kk = 0; kk < 2; ++kk){
      short8 af[4], bfr[4];
      #pragma unroll
      for (int mi=0; mi<4; ++mi){
        int row = wm + mi*16 + lr;
        int g = (kk*4 + lk) ^ (row & 7);
        af[mi] = *(const short8*)&As[row*64 + g*8];
      }
      #pragma unroll
      for (int ni=0; ni<4; ++ni){
        int row = wn + ni*16 + lr;
        int g = (kk*4 + lk) ^ (row & 7);
        bfr[ni] = *(const short8*)&Bs[row*64 + g*8];
      }
      #pragma unroll
      for (int mi=0; mi<4; ++mi)
        #pragma unroll
        for (int ni=0; ni<4; ++ni)
          acc[mi][ni] = __builtin_amdgcn_mfma_f32_16x16x32_bf16(af[mi], bfr[ni], acc[mi][ni], 0,0,0);
    }
    __syncthreads();
  }

  // attention logits while acc is hot: head owned by this wave
  int hh = (bn + wn) >> 6;
  float as_c[4], ad_c[4];
  #pragma unroll
  for (int ni=0; ni<4; ++ni){
    int c = hh*64 + ni*16 + lr;
    as_c[ni] = a_s[c];
    ad_c[ni] = a_d[c];
  }
  #pragma unroll
  for (int mi=0; mi<4; ++mi)
    #pragma unroll
    for (int r=0; r<4; ++r){
      float s = acc[mi][0][r]*as_c[0] + acc[mi][1][r]*as_c[1]
              + acc[mi][2][r]*as_c[2] + acc[mi][3][r]*as_c[3];
      float d = acc[mi][0][r]*ad_c[0] + acc[mi][1][r]*ad_c[1]
              + acc[mi][2][r]*ad_c[2] + acc[mi][3][r]*ad_c[3];
      #pragma unroll
      for (int o=1;o<16;o<<=1){ s += __shfl_xor(s, o); d += __shfl_xor(d, o); }
      if (lr == 0){
        int rowg = bm + wm + mi*16 + lk*4 + r;
        als[rowg*HEADS+hh] = s;
        ald[rowg*HEADS+hh] = d;
      }
    }

  // C write: col = lane&15, row = (lane>>4)*4 + reg   (m89 layout)
  #pragma unroll
  for (int mi=0; mi<4; ++mi)
    #pragma unroll
    for (int ni=0; ni<4; ++ni){
      int col = bn + wn + ni*16 + lr;
      #pragma unroll
      for (int r=0; r<4; ++r){
        int rowg = bm + wm + mi*16 + lk*4 + r;
        C[(size_t)rowg*N + col] = __float2bfloat16(acc[mi][ni][r]);
      }
    }
}

// ---------------- head part 1: per-16-node partial sums (vectorized) ----------------
__global__ __launch_bounds__(256) void k_gemb1(const bf16* __restrict__ h, float* __restrict__ pgemb){
  int gs_ = blockIdx.x;                 // g*8+s, 1024 blocks
  int g = gs_ >> 3, s = gs_ & 7;
  int t = threadIdx.x;
  int c = t & 63, rg = t >> 6;          // 4 row-groups of 16 rows
  const bf16* base = h + ((size_t)(g*NPG_ + s*64 + rg*16))*FDIM;
  float acc[8] = {};
  #pragma unroll 4
  for (int i=0;i<16;i++){
    short8 v = ((const short8*)(base + (size_t)i*FDIM))[c];
    #pragma unroll
    for (int j=0;j<8;j++) acc[j] += bf(v[j]);
  }
  float* dst = pgemb + ((size_t)(gs_*4 + rg))*FDIM + c*8;
  float4 lo = {acc[0],acc[1],acc[2],acc[3]};
  float4 hi = {acc[4],acc[5],acc[6],acc[7]};
  *(float4*)dst = lo;
  *(float4*)(dst+4) = hi;
}

// ---- head part 2: FC1 partials, K-split 8x over 64-wide chunks of EACH half ----
// Block (g,q): agent rows use fc1w rows [q*64, q*64+64) (comb k in [0,512));
// graph part uses fc1w rows [512+q*64, 512+q*64+64). All indices in-bounds.
__global__ __launch_bounds__(256) void k_head1(const bf16* __restrict__ h,
                                               const float* __restrict__ pgemb,
                                               const float* __restrict__ fc1w,
                                               float* __restrict__ pf1,
                                               float* __restrict__ pge){
  __shared__ float ge[64];
  __shared__ float ag[8][64];
  int blk = blockIdx.x;                 // g*8 + q
  int g = blk >> 3, q = blk & 7;
  int t = threadIdx.x;
  int k0 = q*64;

  if (t < 64){
    float s = 0.f;
    const float* p = pgemb + ((size_t)g*32)*FDIM + k0 + t;
    #pragma unroll 8
    for (int c=0;c<32;c++) s += p[(size_t)c*FDIM];
    ge[t] = s * (1.f/NPG_);
  } else if (t < 128){
    int i = t - 64;                     // 64 units: 8 rows x 8 short8
    int r = i >> 3, c8 = i & 7;
    short8 v = ((const short8*)(h + ((size_t)(g*NPG_ + r))*FDIM + k0))[c8];
    #pragma unroll
    for (int j=0;j<8;j++) ag[r][c8*8+j] = bf(v[j]);
  }
  __syncthreads();

  float acc[8] = {};
  float gacc = 0.f;
  for (int kk=0; kk<64; kk++){
    float wa = fc1w[(size_t)(k0+kk)*256 + t];
    float wg = fc1w[(size_t)(FDIM+k0+kk)*256 + t];
    #pragma unroll
    for (int r=0;r<8;r++) acc[r] += ag[r][kk]*wa;
    gacc += ge[kk]*wg;
  }
  #pragma unroll
  for (int r=0;r<8;r++) pf1[((size_t)q*1024 + g*8 + r)*256 + t] = acc[r];
  pge[((size_t)q*NGRAPH + g)*256 + t] = gacc;
}

// ---------------- head part 3: reduce partials + bias + ReLU + FC2 ----------------
__global__ __launch_bounds__(256) void k_fc2(const float* __restrict__ pf1,
                                             const float* __restrict__ pge,
                                             const float* __restrict__ fc1b,
                                             const float* __restrict__ fc2w,
                                             const float* __restrict__ fc2b,
                                             float* __restrict__ out){
  __shared__ float f1[8][256];
  int g = blockIdx.x, t = threadIdx.x;
  float ges = 0.f;
  #pragma unroll
  for (int q=0;q<8;q++) ges += pge[((size_t)q*NGRAPH + g)*256 + t];
  float b = fc1b[t] + ges;
  #pragma unroll
  for (int r=0;r<8;r++){
    float s = 0.f;
    #pragma unroll
    for (int q=0;q<8;q++) s += pf1[((size_t)q*1024 + g*8 + r)*256 + t];
    f1[r][t] = fmaxf(s + b, 0.f);
  }
  __syncthreads();
  if (t < 128){
    int r = t >> 4, o = (t >> 3) & 1, l = t & 7;
    float s = 0.f;
    for (int k = l; k < 256; k += 8) s += f1[r][k] * fc2w[k*2+o];
    #pragma unroll
    for (int off=4; off; off>>=1) s += __shfl_down(s, off);
    if (l == 0) out[(g*8 + r)*2 + o] = s + fc2b[o];
  }
}

extern "C" void kernel_launch(void* const* d_in, const int* in_sizes, int n_in,
                              void* d_out, int out_size, void* d_ws, size_t ws_size,
                              hipStream_t stream)
{
  const float* x    = (const float*)d_in[0];
  const int*   ei   = (const int*)  d_in[1];
  const float* ea   = (const float*)d_in[2];
  const float* Wl[3]  = {(const float*)d_in[3],  (const float*)d_in[9],  (const float*)d_in[15]};
  const float* Bl[3]  = {(const float*)d_in[4],  (const float*)d_in[10], (const float*)d_in[16]};
  const float* ASl[3] = {(const float*)d_in[5],  (const float*)d_in[11], (const float*)d_in[17]};
  const float* ADl[3] = {(const float*)d_in[6],  (const float*)d_in[12], (const float*)d_in[18]};
  const float* WEl[3] = {(const float*)d_in[7],  (const float*)d_in[13], (const float*)d_in[19]};
  const float* AEl[3] = {(const float*)d_in[8],  (const float*)d_in[14], (const float*)d_in[20]};
  const float* FC1W = (const float*)d_in[21];
  const float* FC1B = (const float*)d_in[22];
  const float* FC2W = (const float*)d_in[23];
  const float* FC2B = (const float*)d_in[24];
  float* out = (float*)d_out;
  (void)in_sizes; (void)n_in;

  char* ws = (char*)d_ws;
  size_t off = 0;
  auto alloc = [&](size_t bytes)->char*{
    char* p = ws + off;
    off = (off + bytes + 255) & ~(size_t)255;
    return p;
  };
  bf16*  h       = (bf16*) alloc((size_t)NN*FDIM*2);    // 64 MB
  bf16*  xs      = (bf16*) alloc((size_t)NN*FDIM*2);    // 64 MB
  float* als     = (float*)alloc((size_t)NN*HEADS*4);   // 2 MB
  float* ald     = (float*)alloc((size_t)NN*HEADS*4);   // 2 MB
  float* la      = (float*)alloc((size_t)NN*4);
  int*   deg     = (int*)  alloc((size_t)NN*4);
  int*   row_ptr = (int*)  alloc((size_t)NN*4);
  int*   esrc    = (int*)  alloc((size_t)ETOT*4);
  float* eattr   = (float*)alloc((size_t)ETOT*4);
  float* coef    = (float*)alloc(3*HEADS*4);
  float* wsd     = (float*)alloc(48*4);
  bf16*  wt      = (bf16*) alloc((size_t)2*FDIM*FDIM*2);  // layers 2,3 transposed bf16
  float* pgemb   = (float*)alloc((size_t)NGRAPH*32*FDIM*4); // 8 MB
  float* pf1     = (float*)alloc((size_t)8*1024*256*4);     // 8 MB
  float* pge     = (float*)alloc((size_t)8*NGRAPH*256*4);   // 1 MB

  if (off > ws_size){
    k_sentinel<<<(out_size+255)/256, 256, 0, stream>>>(out, out_size);
    return;
  }

  // ---- CSR build + coef + layer1 ws/wd: one kernel ----
  k_csr<<<NGRAPH+4, 512, 0, stream>>>(ei, ea, WEl[0], AEl[0], WEl[1], AEl[1], WEl[2], AEl[2],
                                      Wl[0], ASl[0], ADl[0],
                                      deg, row_ptr, la, esrc, eattr, coef, wsd);
  k_wt<<<(2*FDIM*FDIM+255)/256, 256, 0, stream>>>(Wl[1], Wl[2], wt);

  // ---- layer 1: fully fused in x-space ----
  k_gat1<<<NN/4, 256, 0, stream>>>(x, Wl[0], wsd, coef, row_ptr, deg, esrc, eattr, Bl[0], h);

  // ---- layers 2,3: GEMM (+ fused logits) then gather-aggregate ----
  for (int l=1;l<3;l++){
    gemm_mfma<<<2048, 256, 0, stream>>>(h, wt + (size_t)(l-1)*FDIM*FDIM,
                                        ASl[l], ADl[l], xs, als, ald, NN, FDIM, FDIM);
    k_gat<<<NN/4, 256, 0, stream>>>(xs, als, ald, coef + l*HEADS, row_ptr, deg, esrc, eattr, la, Bl[l], h);
  }

  // ---- head ----
  k_gemb1<<<NGRAPH*8, 256, 0, stream>>>(h, pgemb);
  k_head1<<<NGRAPH*8, 256, 0, stream>>>(h, pgemb, FC1W, pf1, pge);
  k_fc2 <<<NGRAPH, 256, 0, stream>>>(pf1, pge, FC1B, FC2W, FC2B, out);
}